// Round 1
// 174.660 us; speedup vs baseline: 1.0026x; 1.0026x over previous
//
#include <hip/hip_runtime.h>

typedef __attribute__((ext_vector_type(8))) short bf16x8;
typedef __attribute__((ext_vector_type(4))) float floatx4;

static constexpr int SEQ    = 2048;
static constexpr int CDIM   = 1024;
static constexpr int NH     = 16;
static constexpr int HD     = 64;
static constexpr int NBATCH = 2;
static constexpr int MROWS  = NBATCH * SEQ;   // 4096

static __device__ __forceinline__ short f2bf(float f) {
    union { float f; unsigned u; } x; x.f = f;
    unsigned r = x.u + 0x7fffu + ((x.u >> 16) & 1u);   // RNE
    return (short)(r >> 16);
}

static __device__ __forceinline__ unsigned pack2bf(float lo, float hi) {
    return ((unsigned)(unsigned short)f2bf(hi) << 16) | (unsigned)(unsigned short)f2bf(lo);
}

// fast pack: 2 adds + v_perm (round-half-up)
static __device__ __forceinline__ unsigned pk2(float lo, float hi) {
    union { float f; unsigned u; } a, b; a.f = lo; b.f = hi;
    return __builtin_amdgcn_perm(b.u + 0x8000u, a.u + 0x8000u, 0x07060302u);
}

static __device__ __forceinline__ float bf2f(short s) {
    union { unsigned u; float f; } x;
    x.u = ((unsigned)(unsigned short)s) << 16;
    return x.f;
}

static __device__ __forceinline__ floatx4 mfma16(bf16x8 a, bf16x8 b, floatx4 c) {
    return __builtin_amdgcn_mfma_f32_16x16x32_bf16(a, b, c, 0, 0, 0);
}

static __device__ __forceinline__ bf16x8 mk8(unsigned d0, unsigned d1, unsigned d2, unsigned d3) {
    union { unsigned u[4]; bf16x8 v; } x;
    x.u[0] = d0; x.u[1] = d1; x.u[2] = d2; x.u[3] = d3;
    return x.v;
}

// async global->LDS, 16B per lane; LDS dest = wave-uniform base + lane*16
static __device__ __forceinline__ void gl_lds16(const short* g, short* l) {
    __builtin_amdgcn_global_load_lds(
        (const __attribute__((address_space(1))) void*)g,
        (__attribute__((address_space(3))) void*)l, 16, 0, 0);
}

// ---------------------------------------------------------------------------
// Fused dtype-detect + canonicalize-to-bf16 for all 5 inputs (one launch).
__global__ void convert_all(
    const void* __restrict__ x,  const void* __restrict__ wq,
    const void* __restrict__ wk, const void* __restrict__ wv,
    const void* __restrict__ wo,
    short* __restrict__ xc,  short* __restrict__ wqc, short* __restrict__ wkc,
    short* __restrict__ wvc, short* __restrict__ woc,
    int* __restrict__ flag)
{
    const int tid = threadIdx.x;
    const unsigned short* xs = (const unsigned short*)x;
    int pl = 0;
    for (int i = tid; i < 2048; i += 256) {
        const int e = (xs[2 * i] >> 7) & 0xFF;
        if (e >= 110 && e <= 144) pl++;
    }
    #pragma unroll
    for (int off = 32; off > 0; off >>= 1) pl += __shfl_down(pl, off, 64);
    __shared__ int cnt;
    if (tid == 0) cnt = 0;
    __syncthreads();
    if ((tid & 63) == 0) atomicAdd(&cnt, pl);
    __syncthreads();
    const int f = (cnt < 1024) ? 1 : 0;   // <50% plausible -> f32 input
    if (blockIdx.x == 0 && blockIdx.y == 0 && tid == 0) *flag = f;

    const int y = blockIdx.y;
    const void* src = (y == 0) ? x  : (y == 1) ? wq : (y == 2) ? wk : (y == 3) ? wv : wo;
    short*      dst = (y == 0) ? xc : (y == 1) ? wqc : (y == 2) ? wkc : (y == 3) ? wvc : woc;
    const int n4 = (y == 0) ? (MROWS * CDIM / 4) : (CDIM * CDIM / 4);

    const int stride = gridDim.x * blockDim.x;
    for (int i = blockIdx.x * blockDim.x + tid; i < n4; i += stride) {
        if (f) {
            const float4 v = ((const float4*)src)[i];
            ((uint2*)dst)[i] = make_uint2(pack2bf(v.x, v.y), pack2bf(v.z, v.w));
        } else {
            ((uint2*)dst)[i] = ((const uint2*)src)[i];
        }
    }
}

// ---------------------------------------------------------------------------
// NT-GEMM 128x128, BK=64, global_load_lds staging with XOR bank swizzle.
// sel==2 && VT: write output transposed to VT[b][h][d][key] (attention V).
__global__ __launch_bounds__(256) void gemm_bt128(
    const short* __restrict__ A,
    const short* __restrict__ W0, const short* __restrict__ W1, const short* __restrict__ W2,
    void* __restrict__ C0, void* __restrict__ C1, void* __restrict__ C2,
    short* __restrict__ VT, const int* __restrict__ flag)
{
    const int m0  = blockIdx.x * 128;
    const int sel = blockIdx.y >> 3;
    const int n0  = (blockIdx.y & 7) * 128;
    const short* W = (sel == 0) ? W0 : ((sel == 1) ? W1 : W2);
    void*        C = (sel == 0) ? C0 : ((sel == 1) ? C1 : C2);
    const bool f32out = (flag != nullptr) && (*flag != 0);
    const bool vtout  = (sel == 2) && (VT != nullptr);

    __shared__ __align__(16) short ta[128 * 64];   // 16 KB
    __shared__ __align__(16) short tb[128 * 64];

    const int tid  = threadIdx.x;
    const int lane = tid & 63;
    const int wave = tid >> 6;
    const int quad = lane >> 4;
    const int l16  = lane & 15;
    const int wm   = (wave >> 1) * 64;
    const int wn   = (wave & 1) * 64;

    floatx4 acc[4][4];
    #pragma unroll
    for (int i = 0; i < 4; i++)
        #pragma unroll
        for (int j = 0; j < 4; j++)
            acc[i][j] = 0.0f;

    const int sr8 = lane >> 3;
    const int ug  = ((lane & 7) ^ sr8) * 8;
    const short* Ab = A + (size_t)(m0 + 32 * wave + sr8) * CDIM + ug;
    const short* Wb = W + (size_t)(n0 + 32 * wave + sr8) * CDIM + ug;
    short* ta0 = ta + (32 * wave) * 64;
    short* tb0 = tb + (32 * wave) * 64;

    for (int k0 = 0; k0 < CDIM; k0 += 64) {
        __syncthreads();                       // prev iter frag reads done
        gl_lds16(Ab + k0,             ta0);
        gl_lds16(Ab +  8 * CDIM + k0, ta0 +  8 * 64);
        gl_lds16(Ab + 16 * CDIM + k0, ta0 + 16 * 64);
        gl_lds16(Ab + 24 * CDIM + k0, ta0 + 24 * 64);
        gl_lds16(Wb + k0,             tb0);
        gl_lds16(Wb +  8 * CDIM + k0, tb0 +  8 * 64);
        gl_lds16(Wb + 16 * CDIM + k0, tb0 + 16 * 64);
        gl_lds16(Wb + 24 * CDIM + k0, tb0 + 24 * 64);
        __syncthreads();                       // vmcnt drained -> LDS ready

        #pragma unroll
        for (int kc = 0; kc < 2; kc++) {
            const int pu = (((kc * 4 + quad) ^ (l16 & 7))) * 8;  // un-swizzle
            bf16x8 af[4], bw[4];
            #pragma unroll
            for (int i = 0; i < 4; i++)
                af[i] = *(const bf16x8*)(ta + (wm + i * 16 + l16) * 64 + pu);
            #pragma unroll
            for (int j = 0; j < 4; j++)
                bw[j] = *(const bf16x8*)(tb + (wn + j * 16 + l16) * 64 + pu);
            #pragma unroll
            for (int i = 0; i < 4; i++)
                #pragma unroll
                for (int j = 0; j < 4; j++)
                    acc[i][j] = mfma16(af[i], bw[j], acc[i][j]);
        }
    }

    #pragma unroll
    for (int i = 0; i < 4; i++) {
        #pragma unroll
        for (int j = 0; j < 4; j++) {
            const int row0 = m0 + wm + i * 16 + quad * 4;       // +r
            const int col  = n0 + wn + j * 16 + l16;
            if (vtout) {
                const int bb  = row0 >> 11;
                const int key = row0 & 2047;
                const size_t idx = ((size_t)(bb * 1024 + col)) * 2048 + key;
                *(uint2*)(VT + idx) = make_uint2(pk2(acc[i][j][0], acc[i][j][1]),
                                                 pk2(acc[i][j][2], acc[i][j][3]));
            } else if (f32out) {
                float* cp = (float*)C + (size_t)row0 * CDIM + col;
                #pragma unroll
                for (int r = 0; r < 4; r++)
                    cp[(size_t)r * CDIM] = acc[i][j][r];
            } else {
                short* cp = (short*)C + (size_t)row0 * CDIM + col;
                #pragma unroll
                for (int r = 0; r < 4; r++)
                    cp[(size_t)r * CDIM] = f2bf(acc[i][j][r]);
            }
        }
    }
}

// ---------------------------------------------------------------------------
// NT-GEMM 128x64 tile (for the N=1024 O-projection: 512 blocks = 2/CU instead
// of 256 = 1/CU). Same staging/swizzle recipe; waves 2x2 over (128m, 64n).
__global__ __launch_bounds__(256) void gemm_n64(
    const short* __restrict__ A, const short* __restrict__ W,
    void* __restrict__ C, const int* __restrict__ flag)
{
    const int m0 = blockIdx.x * 128;
    const int n0 = blockIdx.y * 64;
    const bool f32out = (flag != nullptr) && (*flag != 0);

    __shared__ __align__(16) short ta[128 * 64];   // 16 KB
    __shared__ __align__(16) short tb[64 * 64];    //  8 KB

    const int tid  = threadIdx.x;
    const int lane = tid & 63;
    const int wave = tid >> 6;
    const int quad = lane >> 4;
    const int l16  = lane & 15;
    const int wm   = (wave >> 1) * 64;
    const int wn   = (wave & 1) * 32;

    floatx4 acc[4][2];
    #pragma unroll
    for (int i = 0; i < 4; i++)
        #pragma unroll
        for (int j = 0; j < 2; j++)
            acc[i][j] = 0.0f;

    const int sr8 = lane >> 3;
    const int ug  = ((lane & 7) ^ sr8) * 8;
    const short* Ab = A + (size_t)(m0 + 32 * wave + sr8) * CDIM + ug;
    const short* Wb = W + (size_t)(n0 + 16 * wave + sr8) * CDIM + ug;
    short* ta0 = ta + (32 * wave) * 64;
    short* tb0 = tb + (16 * wave) * 64;

    for (int k0 = 0; k0 < CDIM; k0 += 64) {
        __syncthreads();
        gl_lds16(Ab + k0,             ta0);
        gl_lds16(Ab +  8 * CDIM + k0, ta0 +  8 * 64);
        gl_lds16(Ab + 16 * CDIM + k0, ta0 + 16 * 64);
        gl_lds16(Ab + 24 * CDIM + k0, ta0 + 24 * 64);
        gl_lds16(Wb + k0,             tb0);
        gl_lds16(Wb +  8 * CDIM + k0, tb0 +  8 * 64);
        __syncthreads();

        #pragma unroll
        for (int kc = 0; kc < 2; kc++) {
            const int pu = (((kc * 4 + quad) ^ (l16 & 7))) * 8;
            bf16x8 af[4], bw[2];
            #pragma unroll
            for (int i = 0; i < 4; i++)
                af[i] = *(const bf16x8*)(ta + (wm + i * 16 + l16) * 64 + pu);
            #pragma unroll
            for (int j = 0; j < 2; j++)
                bw[j] = *(const bf16x8*)(tb + (wn + j * 16 + l16) * 64 + pu);
            #pragma unroll
            for (int i = 0; i < 4; i++)
                #pragma unroll
                for (int j = 0; j < 2; j++)
                    acc[i][j] = mfma16(af[i], bw[j], acc[i][j]);
        }
    }

    #pragma unroll
    for (int i = 0; i < 4; i++) {
        #pragma unroll
        for (int j = 0; j < 2; j++) {
            const int row0 = m0 + wm + i * 16 + quad * 4;
            const int col  = n0 + wn + j * 16 + l16;
            if (f32out) {
                float* cp = (float*)C + (size_t)row0 * CDIM + col;
                #pragma unroll
                for (int r = 0; r < 4; r++)
                    cp[(size_t)r * CDIM] = acc[i][j][r];
            } else {
                short* cp = (short*)C + (size_t)row0 * CDIM + col;
                #pragma unroll
                for (int r = 0; r < 4; r++)
                    cp[(size_t)r * CDIM] = f2bf(acc[i][j][r]);
            }
        }
    }
}

// ---------------------------------------------------------------------------
// Flash attention, S^T form, fixed-max softmax, 2-way K-SPLIT.
// v2: P never touches LDS. PV's k-slot meaning is permuted so the QK^T output
// fragment IS the PV B-operand: k-slot (quad,e) of kc <-> key
// 32*kc + 16*(e>>2) + 4*quad + (e&3). V is staged into LDS with the matching
// column permutation (pure data-relabel; reduction order change only).
// Pl buffer (34.8 KB) deleted -> LDS 35840 B -> 4 blocks/CU (was 2).
__global__ __launch_bounds__(256, 4) void attn_t(
    const short* __restrict__ Q, const short* __restrict__ K,
    const short* __restrict__ VT,
    short* __restrict__ P0, short* __restrict__ P1, float* __restrict__ L)
{
    const int h = blockIdx.x;
    const int b = blockIdx.y;
    // z -> (qt2, p): snake-balanced quadruples; with 4 blocks/CU resident the
    // co-resident items {z,15-z,z+16,31-z} sum to ~17 tile-iters per CU.
    const int z = blockIdx.z;
    const int g = z >> 3;
    const int item = (g == 1) ? (23 - z) : (g == 3) ? (55 - z) : z;
    const int qt2 = 15 - (item >> 1);
    const int p   = item & 1;
    const int nktall = qt2 + 1;               // total 128-key tiles for supertile

    const int tid  = threadIdx.x;
    const int lane = tid & 63;
    const int wave = tid >> 6;
    const int quad = lane >> 4;
    const int l16  = lane & 15;

    __shared__ __align__(16) short Kt[128][72];       // K tile [key][d]      18432 B
    __shared__ __align__(16) short Vt[64][136];       // V^T tile [d][pkey]   17408 B

    const int rowBase = b * SEQ;
    const int colH    = h * HD;
    const int qgA     = qt2 * 128 + wave * 16 + l16;  // strip A q row
    const int qgB     = qgA + 64;                     // strip B q row

    bf16x8 qa0, qa1, qc0, qc1;
    {
        const short* qp = Q + (size_t)(rowBase + qgA) * CDIM + colH + quad * 8;
        qa0 = *(const bf16x8*)qp;
        qa1 = *(const bf16x8*)(qp + 32);
        const short* qp2 = qp + (size_t)64 * CDIM;
        qc0 = *(const bf16x8*)qp2;
        qc1 = *(const bf16x8*)(qp2 + 32);
    }

    floatx4 oA[4], oB[4];
    #pragma unroll
    for (int nd = 0; nd < 4; nd++) { oA[nd] = 0.0f; oB[nd] = 0.0f; }
    float lA = 0.0f, lB = 0.0f;

    // K staging: thread t -> key = t>>1, d-chunk (t&1)*32 (4 x b128)
    const int kk = tid >> 1;
    const int kd = (tid & 1) * 32;
    const short* kg = K + (size_t)(rowBase + kk) * CDIM + colH + kd;
    // V^T staging: thread t -> d = t>>2, 32-key chunk (t&3)*32 (4 x b128 load,
    // 8 x b64 permuted store)
    const int sd = tid >> 2;
    const int sk = (tid & 3) * 32;
    const short* vg = VT + ((size_t)(b * NH + h) * HD + sd) * SEQ + sk;

    // prefetch first tile of this split into NAMED registers (no arrays: spill)
    const short* kg0 = kg + (size_t)p * 128 * CDIM;
    const short* vg0 = vg + p * 128;
    uint4 ka_0 = *(const uint4*)(kg0);
    uint4 ka_1 = *(const uint4*)(kg0 + 8);
    uint4 ka_2 = *(const uint4*)(kg0 + 16);
    uint4 ka_3 = *(const uint4*)(kg0 + 24);
    uint4 va_0 = *(const uint4*)(vg0);
    uint4 va_1 = *(const uint4*)(vg0 + 8);
    uint4 va_2 = *(const uint4*)(vg0 + 16);
    uint4 va_3 = *(const uint4*)(vg0 + 24);

    const float SCL = 0.18033688011112042f;   // 0.125 * log2(e)

    for (int kt = p; kt < nktall; kt += 2) {
        __syncthreads();                 // prev tile's LDS reads done
        *(uint4*)&Kt[kk][kd]      = ka_0;
        *(uint4*)&Kt[kk][kd + 8]  = ka_1;
        *(uint4*)&Kt[kk][kd + 16] = ka_2;
        *(uint4*)&Kt[kk][kd + 24] = ka_3;
        // permuted V scatter: key offset o=16h+4q+r -> col 8q+4h+r
        {
            short* vrow = &Vt[sd][sk];
            *(uint2*)(vrow + 0)  = make_uint2(va_0.x, va_0.y);   // keys  0-3
            *(uint2*)(vrow + 8)  = make_uint2(va_0.z, va_0.w);   // keys  4-7
            *(uint2*)(vrow + 16) = make_uint2(va_1.x, va_1.y);   // keys  8-11
            *(uint2*)(vrow + 24) = make_uint2(va_1.z, va_1.w);   // keys 12-15
            *(uint2*)(vrow + 4)  = make_uint2(va_2.x, va_2.y);   // keys 16-19
            *(uint2*)(vrow + 12) = make_uint2(va_2.z, va_2.w);   // keys 20-23
            *(uint2*)(vrow + 20) = make_uint2(va_3.x, va_3.y);   // keys 24-27
            *(uint2*)(vrow + 28) = make_uint2(va_3.z, va_3.w);   // keys 28-31
        }
        __syncthreads();                 // tiles ready

        if (kt + 2 < nktall) {           // prefetch next tile of this split
            const short* kn = kg + (size_t)(kt + 2) * 128 * CDIM;
            const short* vn = vg + (kt + 2) * 128;
            ka_0 = *(const uint4*)(kn);
            ka_1 = *(const uint4*)(kn + 8);
            ka_2 = *(const uint4*)(kn + 16);
            ka_3 = *(const uint4*)(kn + 24);
            va_0 = *(const uint4*)(vn);
            va_1 = *(const uint4*)(vn + 8);
            va_2 = *(const uint4*)(vn + 16);
            va_3 = *(const uint4*)(vn + 24);
        }

        const int key0 = kt * 128;
        const bool masked = (kt == nktall - 1);  // diagonal tile (one split only)

        // QK^T + softmax + fused PV. P stays in registers: even ms -> hold
        // packs; odd ms -> complete kc=ms>>1 fragment and issue PV MFMAs.
        unsigned hA0 = 0, hA1 = 0, hB0 = 0, hB1 = 0;
        #pragma unroll
        for (int ms = 0; ms < 8; ms++) {
            const short* kp = &Kt[ms * 16 + l16][quad * 8];
            bf16x8 k0 = *(const bf16x8*)kp;
            bf16x8 k1 = *(const bf16x8*)(kp + 32);
            floatx4 sA = {0.f, 0.f, 0.f, 0.f};
            floatx4 sB = {0.f, 0.f, 0.f, 0.f};
            sA = mfma16(k0, qa0, sA);
            sB = mfma16(k0, qc0, sB);
            sA = mfma16(k1, qa1, sA);
            sB = mfma16(k1, qc1, sB);
            float pA[4], pB[4];
            #pragma unroll
            for (int r = 0; r < 4; r++) {
                const int kgl = key0 + ms * 16 + quad * 4 + r;
                float eA = exp2f(sA[r] * SCL);
                float eB = exp2f(sB[r] * SCL);
                if (masked) {
                    if (kgl > qgA) eA = 0.0f;
                    if (kgl > qgB) eB = 0.0f;
                }
                pA[r] = eA; lA += eA;
                pB[r] = eB; lB += eB;
            }
            const unsigned cA0 = pk2(pA[0], pA[1]);
            const unsigned cA1 = pk2(pA[2], pA[3]);
            const unsigned cB0 = pk2(pB[0], pB[1]);
            const unsigned cB1 = pk2(pB[2], pB[3]);
            if ((ms & 1) == 0) {
                hA0 = cA0; hA1 = cA1; hB0 = cB0; hB1 = cB1;
            } else {
                const int kc = ms >> 1;
                const bf16x8 pbA = mk8(hA0, hA1, cA0, cA1);
                const bf16x8 pbB = mk8(hB0, hB1, cB0, cB1);
                #pragma unroll
                for (int nd = 0; nd < 4; nd++) {
                    const bf16x8 va = *(const bf16x8*)&Vt[nd * 16 + l16][kc * 32 + quad * 8];
                    oA[nd] = mfma16(va, pbA, oA[nd]);
                    oB[nd] = mfma16(va, pbB, oB[nd]);
                }
            }
        }
    }

    // l reductions across quads (per-lane partial covers keys mod 16)
    lA += __shfl_xor(lA, 16, 64);
    lA += __shfl_xor(lA, 32, 64);
    lB += __shfl_xor(lB, 16, 64);
    lB += __shfl_xor(lB, 32, 64);

    // store UNNORMALIZED partial O (bf16) + l (f32) for this split
    short* Pp = p ? P1 : P0;
    float* Lp = L + p * (NBATCH * NH * SEQ);
    short* opA = Pp + (size_t)(rowBase + qgA) * CDIM + colH;
    short* opB = Pp + (size_t)(rowBase + qgB) * CDIM + colH;
    #pragma unroll
    for (int nd = 0; nd < 4; nd++) {
        *(uint2*)(opA + nd * 16 + quad * 4) =
            make_uint2(pk2(oA[nd][0], oA[nd][1]), pk2(oA[nd][2], oA[nd][3]));
        *(uint2*)(opB + nd * 16 + quad * 4) =
            make_uint2(pk2(oB[nd][0], oB[nd][1]), pk2(oB[nd][2], oB[nd][3]));
    }
    if (quad == 0) {
        Lp[(b * NH + h) * SEQ + qgA] = lA;
        Lp[(b * NH + h) * SEQ + qgB] = lB;
    }
}

// ---------------------------------------------------------------------------
// Combine the two K-split partials: Ob = (P0 + P1) / (l0 + l1), bf16 out.
__global__ void combine(const short* __restrict__ P0, const short* __restrict__ P1,
                        const float* __restrict__ L, short* __restrict__ Ob)
{
    const int i = blockIdx.x * blockDim.x + threadIdx.x;   // 8-short chunk
    const int row = i >> 7;            // 128 chunks per 1024-col row
    const int c8  = i & 127;
    const int h   = c8 >> 3;           // 8 chunks per 64-wide head
    const int b   = row >> 11;
    const int q   = row & 2047;
    const int li  = (b * NH + h) * SEQ + q;
    const float inv = 1.0f / (L[li] + L[NBATCH * NH * SEQ + li]);

    const bf16x8 a0 = ((const bf16x8*)P0)[i];
    const bf16x8 a1 = ((const bf16x8*)P1)[i];
    unsigned d[4];
    #pragma unroll
    for (int e = 0; e < 4; e++) {
        const float lo = (bf2f(a0[2 * e])     + bf2f(a1[2 * e]))     * inv;
        const float hi = (bf2f(a0[2 * e + 1]) + bf2f(a1[2 * e + 1])) * inv;
        d[e] = pk2(lo, hi);
    }
    ((uint4*)Ob)[i] = make_uint4(d[0], d[1], d[2], d[3]);
}

extern "C" void kernel_launch(void* const* d_in, const int* in_sizes, int n_in,
                              void* d_out, int out_size, void* d_ws, size_t ws_size,
                              hipStream_t stream)
{
    const void* x  = d_in[0];
    const void* wq = d_in[1];
    const void* wk = d_in[2];
    const void* wv = d_in[3];
    const void* wo = d_in[4];

    int* flag = (int*)d_ws;
    short* w = (short*)((char*)d_ws + 256);
    const int ME  = 1024 * 1024;
    short* Wqc = w;                            // 4 x 1M elems
    short* Wkc = w + 1 * ME;
    short* Wvc = w + 2 * ME;
    short* Woc = w + 3 * ME;
    short* Xc  = w + 4 * ME;                   // 4M (later: P0 partials -> Ob)
    short* Qb  = w + 8 * ME;
    short* Kb  = w + 12 * ME;
    short* VTb = w + 16 * ME;                  // V^T [b][h][d][key]
    short* P1b = w + 20 * ME;                  // split-1 partial O
    float* Lb  = (float*)(w + 24 * ME);        // 2 x 65536 f32 row sums
    short* P0b = Xc;                           // split-0 partials (Xc dead)
    short* Ob  = Xc;                           // combine writes in place
    // total: 48.5 MB + 256 B

    dim3 blk(256);
    convert_all<<<dim3(512, 5), blk, 0, stream>>>(
        x, wq, wk, wv, wo, Xc, Wqc, Wkc, Wvc, Woc, flag);

    // QKV projection; V written transposed to VTb
    gemm_bt128<<<dim3(MROWS / 128, 24), blk, 0, stream>>>(
        Xc, Wqc, Wkc, Wvc, Qb, Kb, nullptr, VTb, nullptr);
    // causal flash attention, 2-way K-split partials
    attn_t<<<dim3(NH, NBATCH, 32), blk, 0, stream>>>(Qb, Kb, VTb, P0b, P1b, Lb);
    // combine partials -> Ob
    combine<<<dim3(MROWS * CDIM / 8 / 256), blk, 0, stream>>>(P0b, P1b, Lb, Ob);
    // output projection (128x64 tiles -> 512 blocks)
    gemm_n64<<<dim3(MROWS / 128, CDIM / 64), blk, 0, stream>>>(
        Ob, Woc, d_out, flag);
}

// Round 2
// 174.109 us; speedup vs baseline: 1.0058x; 1.0032x over previous
//
#include <hip/hip_runtime.h>

typedef __attribute__((ext_vector_type(8))) short bf16x8;
typedef __attribute__((ext_vector_type(4))) float floatx4;

static constexpr int SEQ    = 2048;
static constexpr int CDIM   = 1024;
static constexpr int NH     = 16;
static constexpr int HD     = 64;
static constexpr int NBATCH = 2;
static constexpr int MROWS  = NBATCH * SEQ;   // 4096

static __device__ __forceinline__ short f2bf(float f) {
    union { float f; unsigned u; } x; x.f = f;
    unsigned r = x.u + 0x7fffu + ((x.u >> 16) & 1u);   // RNE
    return (short)(r >> 16);
}

static __device__ __forceinline__ unsigned pack2bf(float lo, float hi) {
    return ((unsigned)(unsigned short)f2bf(hi) << 16) | (unsigned)(unsigned short)f2bf(lo);
}

// fast pack: 2 adds + v_perm (round-half-up)
static __device__ __forceinline__ unsigned pk2(float lo, float hi) {
    union { float f; unsigned u; } a, b; a.f = lo; b.f = hi;
    return __builtin_amdgcn_perm(b.u + 0x8000u, a.u + 0x8000u, 0x07060302u);
}

static __device__ __forceinline__ float bf2f(short s) {
    union { unsigned u; float f; } x;
    x.u = ((unsigned)(unsigned short)s) << 16;
    return x.f;
}

static __device__ __forceinline__ floatx4 mfma16(bf16x8 a, bf16x8 b, floatx4 c) {
    return __builtin_amdgcn_mfma_f32_16x16x32_bf16(a, b, c, 0, 0, 0);
}

static __device__ __forceinline__ bf16x8 mk8(unsigned d0, unsigned d1, unsigned d2, unsigned d3) {
    union { unsigned u[4]; bf16x8 v; } x;
    x.u[0] = d0; x.u[1] = d1; x.u[2] = d2; x.u[3] = d3;
    return x.v;
}

// async global->LDS, 16B per lane; LDS dest = wave-uniform base + lane*16
static __device__ __forceinline__ void gl_lds16(const short* g, short* l) {
    __builtin_amdgcn_global_load_lds(
        (const __attribute__((address_space(1))) void*)g,
        (__attribute__((address_space(3))) void*)l, 16, 0, 0);
}

// ---------------------------------------------------------------------------
// Fused dtype-detect + canonicalize-to-bf16 for all 5 inputs (one launch).
__global__ void convert_all(
    const void* __restrict__ x,  const void* __restrict__ wq,
    const void* __restrict__ wk, const void* __restrict__ wv,
    const void* __restrict__ wo,
    short* __restrict__ xc,  short* __restrict__ wqc, short* __restrict__ wkc,
    short* __restrict__ wvc, short* __restrict__ woc,
    int* __restrict__ flag)
{
    const int tid = threadIdx.x;
    const unsigned short* xs = (const unsigned short*)x;
    int pl = 0;
    for (int i = tid; i < 2048; i += 256) {
        const int e = (xs[2 * i] >> 7) & 0xFF;
        if (e >= 110 && e <= 144) pl++;
    }
    #pragma unroll
    for (int off = 32; off > 0; off >>= 1) pl += __shfl_down(pl, off, 64);
    __shared__ int cnt;
    if (tid == 0) cnt = 0;
    __syncthreads();
    if ((tid & 63) == 0) atomicAdd(&cnt, pl);
    __syncthreads();
    const int f = (cnt < 1024) ? 1 : 0;   // <50% plausible -> f32 input
    if (blockIdx.x == 0 && blockIdx.y == 0 && tid == 0) *flag = f;

    const int y = blockIdx.y;
    const void* src = (y == 0) ? x  : (y == 1) ? wq : (y == 2) ? wk : (y == 3) ? wv : wo;
    short*      dst = (y == 0) ? xc : (y == 1) ? wqc : (y == 2) ? wkc : (y == 3) ? wvc : woc;
    const int n4 = (y == 0) ? (MROWS * CDIM / 4) : (CDIM * CDIM / 4);

    const int stride = gridDim.x * blockDim.x;
    for (int i = blockIdx.x * blockDim.x + tid; i < n4; i += stride) {
        if (f) {
            const float4 v = ((const float4*)src)[i];
            ((uint2*)dst)[i] = make_uint2(pack2bf(v.x, v.y), pack2bf(v.z, v.w));
        } else {
            ((uint2*)dst)[i] = ((const uint2*)src)[i];
        }
    }
}

// ---------------------------------------------------------------------------
// NT-GEMM 128x128, BK=64, global_load_lds staging with XOR bank swizzle.
// sel==2 && VT: write output transposed to VT[b][h][d][key] (attention V).
__global__ __launch_bounds__(256) void gemm_bt128(
    const short* __restrict__ A,
    const short* __restrict__ W0, const short* __restrict__ W1, const short* __restrict__ W2,
    void* __restrict__ C0, void* __restrict__ C1, void* __restrict__ C2,
    short* __restrict__ VT, const int* __restrict__ flag)
{
    const int m0  = blockIdx.x * 128;
    const int sel = blockIdx.y >> 3;
    const int n0  = (blockIdx.y & 7) * 128;
    const short* W = (sel == 0) ? W0 : ((sel == 1) ? W1 : W2);
    void*        C = (sel == 0) ? C0 : ((sel == 1) ? C1 : C2);
    const bool f32out = (flag != nullptr) && (*flag != 0);
    const bool vtout  = (sel == 2) && (VT != nullptr);

    __shared__ __align__(16) short ta[128 * 64];   // 16 KB
    __shared__ __align__(16) short tb[128 * 64];

    const int tid  = threadIdx.x;
    const int lane = tid & 63;
    const int wave = tid >> 6;
    const int quad = lane >> 4;
    const int l16  = lane & 15;
    const int wm   = (wave >> 1) * 64;
    const int wn   = (wave & 1) * 64;

    floatx4 acc[4][4];
    #pragma unroll
    for (int i = 0; i < 4; i++)
        #pragma unroll
        for (int j = 0; j < 4; j++)
            acc[i][j] = 0.0f;

    const int sr8 = lane >> 3;
    const int ug  = ((lane & 7) ^ sr8) * 8;
    const short* Ab = A + (size_t)(m0 + 32 * wave + sr8) * CDIM + ug;
    const short* Wb = W + (size_t)(n0 + 32 * wave + sr8) * CDIM + ug;
    short* ta0 = ta + (32 * wave) * 64;
    short* tb0 = tb + (32 * wave) * 64;

    for (int k0 = 0; k0 < CDIM; k0 += 64) {
        __syncthreads();                       // prev iter frag reads done
        gl_lds16(Ab + k0,             ta0);
        gl_lds16(Ab +  8 * CDIM + k0, ta0 +  8 * 64);
        gl_lds16(Ab + 16 * CDIM + k0, ta0 + 16 * 64);
        gl_lds16(Ab + 24 * CDIM + k0, ta0 + 24 * 64);
        gl_lds16(Wb + k0,             tb0);
        gl_lds16(Wb +  8 * CDIM + k0, tb0 +  8 * 64);
        gl_lds16(Wb + 16 * CDIM + k0, tb0 + 16 * 64);
        gl_lds16(Wb + 24 * CDIM + k0, tb0 + 24 * 64);
        __syncthreads();                       // vmcnt drained -> LDS ready

        #pragma unroll
        for (int kc = 0; kc < 2; kc++) {
            const int pu = (((kc * 4 + quad) ^ (l16 & 7))) * 8;  // un-swizzle
            bf16x8 af[4], bw[4];
            #pragma unroll
            for (int i = 0; i < 4; i++)
                af[i] = *(const bf16x8*)(ta + (wm + i * 16 + l16) * 64 + pu);
            #pragma unroll
            for (int j = 0; j < 4; j++)
                bw[j] = *(const bf16x8*)(tb + (wn + j * 16 + l16) * 64 + pu);
            #pragma unroll
            for (int i = 0; i < 4; i++)
                #pragma unroll
                for (int j = 0; j < 4; j++)
                    acc[i][j] = mfma16(af[i], bw[j], acc[i][j]);
        }
    }

    #pragma unroll
    for (int i = 0; i < 4; i++) {
        #pragma unroll
        for (int j = 0; j < 4; j++) {
            const int row0 = m0 + wm + i * 16 + quad * 4;       // +r
            const int col  = n0 + wn + j * 16 + l16;
            if (vtout) {
                const int bb  = row0 >> 11;
                const int key = row0 & 2047;
                const size_t idx = ((size_t)(bb * 1024 + col)) * 2048 + key;
                *(uint2*)(VT + idx) = make_uint2(pk2(acc[i][j][0], acc[i][j][1]),
                                                 pk2(acc[i][j][2], acc[i][j][3]));
            } else if (f32out) {
                float* cp = (float*)C + (size_t)row0 * CDIM + col;
                #pragma unroll
                for (int r = 0; r < 4; r++)
                    cp[(size_t)r * CDIM] = acc[i][j][r];
            } else {
                short* cp = (short*)C + (size_t)row0 * CDIM + col;
                #pragma unroll
                for (int r = 0; r < 4; r++)
                    cp[(size_t)r * CDIM] = f2bf(acc[i][j][r]);
            }
        }
    }
}

// ---------------------------------------------------------------------------
// NT-GEMM 128x64 tile (for the N=1024 O-projection: 512 blocks = 2/CU instead
// of 256 = 1/CU). Same staging/swizzle recipe; waves 2x2 over (128m, 64n).
__global__ __launch_bounds__(256) void gemm_n64(
    const short* __restrict__ A, const short* __restrict__ W,
    void* __restrict__ C, const int* __restrict__ flag)
{
    const int m0 = blockIdx.x * 128;
    const int n0 = blockIdx.y * 64;
    const bool f32out = (flag != nullptr) && (*flag != 0);

    __shared__ __align__(16) short ta[128 * 64];   // 16 KB
    __shared__ __align__(16) short tb[64 * 64];    //  8 KB

    const int tid  = threadIdx.x;
    const int lane = tid & 63;
    const int wave = tid >> 6;
    const int quad = lane >> 4;
    const int l16  = lane & 15;
    const int wm   = (wave >> 1) * 64;
    const int wn   = (wave & 1) * 32;

    floatx4 acc[4][2];
    #pragma unroll
    for (int i = 0; i < 4; i++)
        #pragma unroll
        for (int j = 0; j < 2; j++)
            acc[i][j] = 0.0f;

    const int sr8 = lane >> 3;
    const int ug  = ((lane & 7) ^ sr8) * 8;
    const short* Ab = A + (size_t)(m0 + 32 * wave + sr8) * CDIM + ug;
    const short* Wb = W + (size_t)(n0 + 16 * wave + sr8) * CDIM + ug;
    short* ta0 = ta + (32 * wave) * 64;
    short* tb0 = tb + (16 * wave) * 64;

    for (int k0 = 0; k0 < CDIM; k0 += 64) {
        __syncthreads();
        gl_lds16(Ab + k0,             ta0);
        gl_lds16(Ab +  8 * CDIM + k0, ta0 +  8 * 64);
        gl_lds16(Ab + 16 * CDIM + k0, ta0 + 16 * 64);
        gl_lds16(Ab + 24 * CDIM + k0, ta0 + 24 * 64);
        gl_lds16(Wb + k0,             tb0);
        gl_lds16(Wb +  8 * CDIM + k0, tb0 +  8 * 64);
        __syncthreads();

        #pragma unroll
        for (int kc = 0; kc < 2; kc++) {
            const int pu = (((kc * 4 + quad) ^ (l16 & 7))) * 8;
            bf16x8 af[4], bw[2];
            #pragma unroll
            for (int i = 0; i < 4; i++)
                af[i] = *(const bf16x8*)(ta + (wm + i * 16 + l16) * 64 + pu);
            #pragma unroll
            for (int j = 0; j < 2; j++)
                bw[j] = *(const bf16x8*)(tb + (wn + j * 16 + l16) * 64 + pu);
            #pragma unroll
            for (int i = 0; i < 4; i++)
                #pragma unroll
                for (int j = 0; j < 2; j++)
                    acc[i][j] = mfma16(af[i], bw[j], acc[i][j]);
        }
    }

    #pragma unroll
    for (int i = 0; i < 4; i++) {
        #pragma unroll
        for (int j = 0; j < 2; j++) {
            const int row0 = m0 + wm + i * 16 + quad * 4;
            const int col  = n0 + wn + j * 16 + l16;
            if (f32out) {
                float* cp = (float*)C + (size_t)row0 * CDIM + col;
                #pragma unroll
                for (int r = 0; r < 4; r++)
                    cp[(size_t)r * CDIM] = acc[i][j][r];
            } else {
                short* cp = (short*)C + (size_t)row0 * CDIM + col;
                #pragma unroll
                for (int r = 0; r < 4; r++)
                    cp[(size_t)r * CDIM] = f2bf(acc[i][j][r]);
            }
        }
    }
}

// ---------------------------------------------------------------------------
// Flash attention, S^T form, fixed-max softmax, 2-way K-SPLIT.
// v3: same structure as v2 (P in registers, permuted-V PV fusion, no Pl LDS)
// but launch_bounds relaxed to (256,2): v2's (256,4) forced VGPR=64 < the
// ~114-reg live set -> compiler rematerialized + un-hoisted the prefetch
// (TCC unchanged, VALUBusy up, 10us slower). exp via raw v_exp_f32 builtin.
__global__ __launch_bounds__(256, 2) void attn_t(
    const short* __restrict__ Q, const short* __restrict__ K,
    const short* __restrict__ VT,
    short* __restrict__ P0, short* __restrict__ P1, float* __restrict__ L)
{
    const int h = blockIdx.x;
    const int b = blockIdx.y;
    // z -> (qt2, p): snake-balanced quadruples; co-resident items sum ~17
    const int z = blockIdx.z;
    const int g = z >> 3;
    const int item = (g == 1) ? (23 - z) : (g == 3) ? (55 - z) : z;
    const int qt2 = 15 - (item >> 1);
    const int p   = item & 1;
    const int nktall = qt2 + 1;               // total 128-key tiles for supertile

    const int tid  = threadIdx.x;
    const int lane = tid & 63;
    const int wave = tid >> 6;
    const int quad = lane >> 4;
    const int l16  = lane & 15;

    __shared__ __align__(16) short Kt[128][72];       // K tile [key][d]      18432 B
    __shared__ __align__(16) short Vt[64][136];       // V^T tile [d][pkey]   17408 B

    const int rowBase = b * SEQ;
    const int colH    = h * HD;
    const int qgA     = qt2 * 128 + wave * 16 + l16;  // strip A q row
    const int qgB     = qgA + 64;                     // strip B q row

    bf16x8 qa0, qa1, qc0, qc1;
    {
        const short* qp = Q + (size_t)(rowBase + qgA) * CDIM + colH + quad * 8;
        qa0 = *(const bf16x8*)qp;
        qa1 = *(const bf16x8*)(qp + 32);
        const short* qp2 = qp + (size_t)64 * CDIM;
        qc0 = *(const bf16x8*)qp2;
        qc1 = *(const bf16x8*)(qp2 + 32);
    }

    floatx4 oA[4], oB[4];
    #pragma unroll
    for (int nd = 0; nd < 4; nd++) { oA[nd] = 0.0f; oB[nd] = 0.0f; }
    float lA = 0.0f, lB = 0.0f;

    // K staging: thread t -> key = t>>1, d-chunk (t&1)*32 (4 x b128)
    const int kk = tid >> 1;
    const int kd = (tid & 1) * 32;
    const short* kg = K + (size_t)(rowBase + kk) * CDIM + colH + kd;
    // V^T staging: thread t -> d = t>>2, 32-key chunk (t&3)*32 (4 x b128 load,
    // 8 x b64 permuted store)
    const int sd = tid >> 2;
    const int sk = (tid & 3) * 32;
    const short* vg = VT + ((size_t)(b * NH + h) * HD + sd) * SEQ + sk;

    // prefetch first tile of this split into NAMED registers (no arrays: spill)
    const short* kg0 = kg + (size_t)p * 128 * CDIM;
    const short* vg0 = vg + p * 128;
    uint4 ka_0 = *(const uint4*)(kg0);
    uint4 ka_1 = *(const uint4*)(kg0 + 8);
    uint4 ka_2 = *(const uint4*)(kg0 + 16);
    uint4 ka_3 = *(const uint4*)(kg0 + 24);
    uint4 va_0 = *(const uint4*)(vg0);
    uint4 va_1 = *(const uint4*)(vg0 + 8);
    uint4 va_2 = *(const uint4*)(vg0 + 16);
    uint4 va_3 = *(const uint4*)(vg0 + 24);

    const float SCL = 0.18033688011112042f;   // 0.125 * log2(e)

    for (int kt = p; kt < nktall; kt += 2) {
        __syncthreads();                 // prev tile's LDS reads done
        *(uint4*)&Kt[kk][kd]      = ka_0;
        *(uint4*)&Kt[kk][kd + 8]  = ka_1;
        *(uint4*)&Kt[kk][kd + 16] = ka_2;
        *(uint4*)&Kt[kk][kd + 24] = ka_3;
        // permuted V scatter: key offset o=16h+4q+r -> col 8q+4h+r
        {
            short* vrow = &Vt[sd][sk];
            *(uint2*)(vrow + 0)  = make_uint2(va_0.x, va_0.y);   // keys  0-3
            *(uint2*)(vrow + 8)  = make_uint2(va_0.z, va_0.w);   // keys  4-7
            *(uint2*)(vrow + 16) = make_uint2(va_1.x, va_1.y);   // keys  8-11
            *(uint2*)(vrow + 24) = make_uint2(va_1.z, va_1.w);   // keys 12-15
            *(uint2*)(vrow + 4)  = make_uint2(va_2.x, va_2.y);   // keys 16-19
            *(uint2*)(vrow + 12) = make_uint2(va_2.z, va_2.w);   // keys 20-23
            *(uint2*)(vrow + 20) = make_uint2(va_3.x, va_3.y);   // keys 24-27
            *(uint2*)(vrow + 28) = make_uint2(va_3.z, va_3.w);   // keys 28-31
        }
        __syncthreads();                 // tiles ready

        if (kt + 2 < nktall) {           // prefetch next tile of this split
            const short* kn = kg + (size_t)(kt + 2) * 128 * CDIM;
            const short* vn = vg + (kt + 2) * 128;
            ka_0 = *(const uint4*)(kn);
            ka_1 = *(const uint4*)(kn + 8);
            ka_2 = *(const uint4*)(kn + 16);
            ka_3 = *(const uint4*)(kn + 24);
            va_0 = *(const uint4*)(vn);
            va_1 = *(const uint4*)(vn + 8);
            va_2 = *(const uint4*)(vn + 16);
            va_3 = *(const uint4*)(vn + 24);
        }

        const int key0 = kt * 128;
        const bool masked = (kt == nktall - 1);  // diagonal tile (one split only)

        // QK^T + softmax + fused PV. P stays in registers: even ms -> hold
        // packs; odd ms -> complete kc=ms>>1 fragment and issue PV MFMAs.
        unsigned hA0 = 0, hA1 = 0, hB0 = 0, hB1 = 0;
        #pragma unroll
        for (int ms = 0; ms < 8; ms++) {
            const short* kp = &Kt[ms * 16 + l16][quad * 8];
            bf16x8 k0 = *(const bf16x8*)kp;
            bf16x8 k1 = *(const bf16x8*)(kp + 32);
            floatx4 sA = {0.f, 0.f, 0.f, 0.f};
            floatx4 sB = {0.f, 0.f, 0.f, 0.f};
            sA = mfma16(k0, qa0, sA);
            sB = mfma16(k0, qc0, sB);
            sA = mfma16(k1, qa1, sA);
            sB = mfma16(k1, qc1, sB);
            float pA[4], pB[4];
            #pragma unroll
            for (int r = 0; r < 4; r++) {
                const int kgl = key0 + ms * 16 + quad * 4 + r;
                float eA = __builtin_amdgcn_exp2f(sA[r] * SCL);
                float eB = __builtin_amdgcn_exp2f(sB[r] * SCL);
                if (masked) {
                    if (kgl > qgA) eA = 0.0f;
                    if (kgl > qgB) eB = 0.0f;
                }
                pA[r] = eA; lA += eA;
                pB[r] = eB; lB += eB;
            }
            const unsigned cA0 = pk2(pA[0], pA[1]);
            const unsigned cA1 = pk2(pA[2], pA[3]);
            const unsigned cB0 = pk2(pB[0], pB[1]);
            const unsigned cB1 = pk2(pB[2], pB[3]);
            if ((ms & 1) == 0) {
                hA0 = cA0; hA1 = cA1; hB0 = cB0; hB1 = cB1;
            } else {
                const int kc = ms >> 1;
                const bf16x8 pbA = mk8(hA0, hA1, cA0, cA1);
                const bf16x8 pbB = mk8(hB0, hB1, cB0, cB1);
                #pragma unroll
                for (int nd = 0; nd < 4; nd++) {
                    const bf16x8 va = *(const bf16x8*)&Vt[nd * 16 + l16][kc * 32 + quad * 8];
                    oA[nd] = mfma16(va, pbA, oA[nd]);
                    oB[nd] = mfma16(va, pbB, oB[nd]);
                }
            }
        }
    }

    // l reductions across quads (per-lane partial covers keys mod 16)
    lA += __shfl_xor(lA, 16, 64);
    lA += __shfl_xor(lA, 32, 64);
    lB += __shfl_xor(lB, 16, 64);
    lB += __shfl_xor(lB, 32, 64);

    // store UNNORMALIZED partial O (bf16) + l (f32) for this split
    short* Pp = p ? P1 : P0;
    float* Lp = L + p * (NBATCH * NH * SEQ);
    short* opA = Pp + (size_t)(rowBase + qgA) * CDIM + colH;
    short* opB = Pp + (size_t)(rowBase + qgB) * CDIM + colH;
    #pragma unroll
    for (int nd = 0; nd < 4; nd++) {
        *(uint2*)(opA + nd * 16 + quad * 4) =
            make_uint2(pk2(oA[nd][0], oA[nd][1]), pk2(oA[nd][2], oA[nd][3]));
        *(uint2*)(opB + nd * 16 + quad * 4) =
            make_uint2(pk2(oB[nd][0], oB[nd][1]), pk2(oB[nd][2], oB[nd][3]));
    }
    if (quad == 0) {
        Lp[(b * NH + h) * SEQ + qgA] = lA;
        Lp[(b * NH + h) * SEQ + qgB] = lB;
    }
}

// ---------------------------------------------------------------------------
// Combine the two K-split partials: Ob = (P0 + P1) / (l0 + l1), bf16 out.
__global__ void combine(const short* __restrict__ P0, const short* __restrict__ P1,
                        const float* __restrict__ L, short* __restrict__ Ob)
{
    const int i = blockIdx.x * blockDim.x + threadIdx.x;   // 8-short chunk
    const int row = i >> 7;            // 128 chunks per 1024-col row
    const int c8  = i & 127;
    const int h   = c8 >> 3;           // 8 chunks per 64-wide head
    const int b   = row >> 11;
    const int q   = row & 2047;
    const int li  = (b * NH + h) * SEQ + q;
    const float inv = 1.0f / (L[li] + L[NBATCH * NH * SEQ + li]);

    const bf16x8 a0 = ((const bf16x8*)P0)[i];
    const bf16x8 a1 = ((const bf16x8*)P1)[i];
    unsigned d[4];
    #pragma unroll
    for (int e = 0; e < 4; e++) {
        const float lo = (bf2f(a0[2 * e])     + bf2f(a1[2 * e]))     * inv;
        const float hi = (bf2f(a0[2 * e + 1]) + bf2f(a1[2 * e + 1])) * inv;
        d[e] = pk2(lo, hi);
    }
    ((uint4*)Ob)[i] = make_uint4(d[0], d[1], d[2], d[3]);
}

extern "C" void kernel_launch(void* const* d_in, const int* in_sizes, int n_in,
                              void* d_out, int out_size, void* d_ws, size_t ws_size,
                              hipStream_t stream)
{
    const void* x  = d_in[0];
    const void* wq = d_in[1];
    const void* wk = d_in[2];
    const void* wv = d_in[3];
    const void* wo = d_in[4];

    int* flag = (int*)d_ws;
    short* w = (short*)((char*)d_ws + 256);
    const int ME  = 1024 * 1024;
    short* Wqc = w;                            // 4 x 1M elems
    short* Wkc = w + 1 * ME;
    short* Wvc = w + 2 * ME;
    short* Woc = w + 3 * ME;
    short* Xc  = w + 4 * ME;                   // 4M (later: P0 partials -> Ob)
    short* Qb  = w + 8 * ME;
    short* Kb  = w + 12 * ME;
    short* VTb = w + 16 * ME;                  // V^T [b][h][d][key]
    short* P1b = w + 20 * ME;                  // split-1 partial O
    float* Lb  = (float*)(w + 24 * ME);        // 2 x 65536 f32 row sums
    short* P0b = Xc;                           // split-0 partials (Xc dead)
    short* Ob  = Xc;                           // combine writes in place
    // total: 48.5 MB + 256 B

    dim3 blk(256);
    convert_all<<<dim3(512, 5), blk, 0, stream>>>(
        x, wq, wk, wv, wo, Xc, Wqc, Wkc, Wvc, Woc, flag);

    // QKV projection; V written transposed to VTb
    gemm_bt128<<<dim3(MROWS / 128, 24), blk, 0, stream>>>(
        Xc, Wqc, Wkc, Wvc, Qb, Kb, nullptr, VTb, nullptr);
    // causal flash attention, 2-way K-split partials
    attn_t<<<dim3(NH, NBATCH, 32), blk, 0, stream>>>(Qb, Kb, VTb, P0b, P1b, Lb);
    // combine partials -> Ob
    combine<<<dim3(MROWS * CDIM / 8 / 256), blk, 0, stream>>>(P0b, P1b, Lb, Ob);
    // output projection (128x64 tiles -> 512 blocks)
    gemm_n64<<<dim3(MROWS / 128, CDIM / 64), blk, 0, stream>>>(
        Ob, Woc, d_out, flag);
}

// Round 4
// 168.503 us; speedup vs baseline: 1.0392x; 1.0333x over previous
//
#include <hip/hip_runtime.h>

typedef __attribute__((ext_vector_type(8))) short bf16x8;
typedef __attribute__((ext_vector_type(4))) float floatx4;

static constexpr int SEQ    = 2048;
static constexpr int CDIM   = 1024;
static constexpr int NH     = 16;
static constexpr int HD     = 64;
static constexpr int NBATCH = 2;
static constexpr int MROWS  = NBATCH * SEQ;   // 4096

static __device__ __forceinline__ short f2bf(float f) {
    union { float f; unsigned u; } x; x.f = f;
    unsigned r = x.u + 0x7fffu + ((x.u >> 16) & 1u);   // RNE
    return (short)(r >> 16);
}

static __device__ __forceinline__ unsigned pack2bf(float lo, float hi) {
    return ((unsigned)(unsigned short)f2bf(hi) << 16) | (unsigned)(unsigned short)f2bf(lo);
}

// fast pack: 2 adds + v_perm (round-half-up)
static __device__ __forceinline__ unsigned pk2(float lo, float hi) {
    union { float f; unsigned u; } a, b; a.f = lo; b.f = hi;
    return __builtin_amdgcn_perm(b.u + 0x8000u, a.u + 0x8000u, 0x07060302u);
}

static __device__ __forceinline__ float bf2f(short s) {
    union { unsigned u; float f; } x;
    x.u = ((unsigned)(unsigned short)s) << 16;
    return x.f;
}

static __device__ __forceinline__ floatx4 mfma16(bf16x8 a, bf16x8 b, floatx4 c) {
    return __builtin_amdgcn_mfma_f32_16x16x32_bf16(a, b, c, 0, 0, 0);
}

static __device__ __forceinline__ bf16x8 mk8(unsigned d0, unsigned d1, unsigned d2, unsigned d3) {
    union { unsigned u[4]; bf16x8 v; } x;
    x.u[0] = d0; x.u[1] = d1; x.u[2] = d2; x.u[3] = d3;
    return x.v;
}

// async global->LDS, 16B per lane; LDS dest = wave-uniform base + lane*16
static __device__ __forceinline__ void gl_lds16(const short* g, short* l) {
    __builtin_amdgcn_global_load_lds(
        (const __attribute__((address_space(1))) void*)g,
        (__attribute__((address_space(3))) void*)l, 16, 0, 0);
}

// ---------------------------------------------------------------------------
// Fused dtype-detect + canonicalize-to-bf16 for all 5 inputs (one launch).
__global__ void convert_all(
    const void* __restrict__ x,  const void* __restrict__ wq,
    const void* __restrict__ wk, const void* __restrict__ wv,
    const void* __restrict__ wo,
    short* __restrict__ xc,  short* __restrict__ wqc, short* __restrict__ wkc,
    short* __restrict__ wvc, short* __restrict__ woc,
    int* __restrict__ flag)
{
    const int tid = threadIdx.x;
    const unsigned short* xs = (const unsigned short*)x;
    int pl = 0;
    for (int i = tid; i < 2048; i += 256) {
        const int e = (xs[2 * i] >> 7) & 0xFF;
        if (e >= 110 && e <= 144) pl++;
    }
    #pragma unroll
    for (int off = 32; off > 0; off >>= 1) pl += __shfl_down(pl, off, 64);
    __shared__ int cnt;
    if (tid == 0) cnt = 0;
    __syncthreads();
    if ((tid & 63) == 0) atomicAdd(&cnt, pl);
    __syncthreads();
    const int f = (cnt < 1024) ? 1 : 0;   // <50% plausible -> f32 input
    if (blockIdx.x == 0 && blockIdx.y == 0 && tid == 0) *flag = f;

    const int y = blockIdx.y;
    const void* src = (y == 0) ? x  : (y == 1) ? wq : (y == 2) ? wk : (y == 3) ? wv : wo;
    short*      dst = (y == 0) ? xc : (y == 1) ? wqc : (y == 2) ? wkc : (y == 3) ? wvc : woc;
    const int n4 = (y == 0) ? (MROWS * CDIM / 4) : (CDIM * CDIM / 4);

    const int stride = gridDim.x * blockDim.x;
    for (int i = blockIdx.x * blockDim.x + tid; i < n4; i += stride) {
        if (f) {
            const float4 v = ((const float4*)src)[i];
            ((uint2*)dst)[i] = make_uint2(pack2bf(v.x, v.y), pack2bf(v.z, v.w));
        } else {
            ((uint2*)dst)[i] = ((const uint2*)src)[i];
        }
    }
}

// ---------------------------------------------------------------------------
// NT-GEMM 128x128, BK=64, global_load_lds staging with XOR bank swizzle.
// sel==2 && VT: write output transposed to VT[b][h][d][key] (attention V).
__global__ __launch_bounds__(256) void gemm_bt128(
    const short* __restrict__ A,
    const short* __restrict__ W0, const short* __restrict__ W1, const short* __restrict__ W2,
    void* __restrict__ C0, void* __restrict__ C1, void* __restrict__ C2,
    short* __restrict__ VT, const int* __restrict__ flag)
{
    const int m0  = blockIdx.x * 128;
    const int sel = blockIdx.y >> 3;
    const int n0  = (blockIdx.y & 7) * 128;
    const short* W = (sel == 0) ? W0 : ((sel == 1) ? W1 : W2);
    void*        C = (sel == 0) ? C0 : ((sel == 1) ? C1 : C2);
    const bool f32out = (flag != nullptr) && (*flag != 0);
    const bool vtout  = (sel == 2) && (VT != nullptr);

    __shared__ __align__(16) short ta[128 * 64];   // 16 KB
    __shared__ __align__(16) short tb[128 * 64];

    const int tid  = threadIdx.x;
    const int lane = tid & 63;
    const int wave = tid >> 6;
    const int quad = lane >> 4;
    const int l16  = lane & 15;
    const int wm   = (wave >> 1) * 64;
    const int wn   = (wave & 1) * 64;

    floatx4 acc[4][4];
    #pragma unroll
    for (int i = 0; i < 4; i++)
        #pragma unroll
        for (int j = 0; j < 4; j++)
            acc[i][j] = 0.0f;

    const int sr8 = lane >> 3;
    const int ug  = ((lane & 7) ^ sr8) * 8;
    const short* Ab = A + (size_t)(m0 + 32 * wave + sr8) * CDIM + ug;
    const short* Wb = W + (size_t)(n0 + 32 * wave + sr8) * CDIM + ug;
    short* ta0 = ta + (32 * wave) * 64;
    short* tb0 = tb + (32 * wave) * 64;

    for (int k0 = 0; k0 < CDIM; k0 += 64) {
        __syncthreads();                       // prev iter frag reads done
        gl_lds16(Ab + k0,             ta0);
        gl_lds16(Ab +  8 * CDIM + k0, ta0 +  8 * 64);
        gl_lds16(Ab + 16 * CDIM + k0, ta0 + 16 * 64);
        gl_lds16(Ab + 24 * CDIM + k0, ta0 + 24 * 64);
        gl_lds16(Wb + k0,             tb0);
        gl_lds16(Wb +  8 * CDIM + k0, tb0 +  8 * 64);
        gl_lds16(Wb + 16 * CDIM + k0, tb0 + 16 * 64);
        gl_lds16(Wb + 24 * CDIM + k0, tb0 + 24 * 64);
        __syncthreads();                       // vmcnt drained -> LDS ready

        #pragma unroll
        for (int kc = 0; kc < 2; kc++) {
            const int pu = (((kc * 4 + quad) ^ (l16 & 7))) * 8;  // un-swizzle
            bf16x8 af[4], bw[4];
            #pragma unroll
            for (int i = 0; i < 4; i++)
                af[i] = *(const bf16x8*)(ta + (wm + i * 16 + l16) * 64 + pu);
            #pragma unroll
            for (int j = 0; j < 4; j++)
                bw[j] = *(const bf16x8*)(tb + (wn + j * 16 + l16) * 64 + pu);
            #pragma unroll
            for (int i = 0; i < 4; i++)
                #pragma unroll
                for (int j = 0; j < 4; j++)
                    acc[i][j] = mfma16(af[i], bw[j], acc[i][j]);
        }
    }

    #pragma unroll
    for (int i = 0; i < 4; i++) {
        #pragma unroll
        for (int j = 0; j < 4; j++) {
            const int row0 = m0 + wm + i * 16 + quad * 4;       // +r
            const int col  = n0 + wn + j * 16 + l16;
            if (vtout) {
                const int bb  = row0 >> 11;
                const int key = row0 & 2047;
                const size_t idx = ((size_t)(bb * 1024 + col)) * 2048 + key;
                *(uint2*)(VT + idx) = make_uint2(pk2(acc[i][j][0], acc[i][j][1]),
                                                 pk2(acc[i][j][2], acc[i][j][3]));
            } else if (f32out) {
                float* cp = (float*)C + (size_t)row0 * CDIM + col;
                #pragma unroll
                for (int r = 0; r < 4; r++)
                    cp[(size_t)r * CDIM] = acc[i][j][r];
            } else {
                short* cp = (short*)C + (size_t)row0 * CDIM + col;
                #pragma unroll
                for (int r = 0; r < 4; r++)
                    cp[(size_t)r * CDIM] = f2bf(acc[i][j][r]);
            }
        }
    }
}

// ---------------------------------------------------------------------------
// NT-GEMM 128x64 tile (for the N=1024 O-projection: 512 blocks = 2/CU instead
// of 256 = 1/CU). Same staging/swizzle recipe; waves 2x2 over (128m, 64n).
__global__ __launch_bounds__(256) void gemm_n64(
    const short* __restrict__ A, const short* __restrict__ W,
    void* __restrict__ C, const int* __restrict__ flag)
{
    const int m0 = blockIdx.x * 128;
    const int n0 = blockIdx.y * 64;
    const bool f32out = (flag != nullptr) && (*flag != 0);

    __shared__ __align__(16) short ta[128 * 64];   // 16 KB
    __shared__ __align__(16) short tb[64 * 64];    //  8 KB

    const int tid  = threadIdx.x;
    const int lane = tid & 63;
    const int wave = tid >> 6;
    const int quad = lane >> 4;
    const int l16  = lane & 15;
    const int wm   = (wave >> 1) * 64;
    const int wn   = (wave & 1) * 32;

    floatx4 acc[4][2];
    #pragma unroll
    for (int i = 0; i < 4; i++)
        #pragma unroll
        for (int j = 0; j < 2; j++)
            acc[i][j] = 0.0f;

    const int sr8 = lane >> 3;
    const int ug  = ((lane & 7) ^ sr8) * 8;
    const short* Ab = A + (size_t)(m0 + 32 * wave + sr8) * CDIM + ug;
    const short* Wb = W + (size_t)(n0 + 16 * wave + sr8) * CDIM + ug;
    short* ta0 = ta + (32 * wave) * 64;
    short* tb0 = tb + (16 * wave) * 64;

    for (int k0 = 0; k0 < CDIM; k0 += 64) {
        __syncthreads();
        gl_lds16(Ab + k0,             ta0);
        gl_lds16(Ab +  8 * CDIM + k0, ta0 +  8 * 64);
        gl_lds16(Ab + 16 * CDIM + k0, ta0 + 16 * 64);
        gl_lds16(Ab + 24 * CDIM + k0, ta0 + 24 * 64);
        gl_lds16(Wb + k0,             tb0);
        gl_lds16(Wb +  8 * CDIM + k0, tb0 +  8 * 64);
        __syncthreads();

        #pragma unroll
        for (int kc = 0; kc < 2; kc++) {
            const int pu = (((kc * 4 + quad) ^ (l16 & 7))) * 8;
            bf16x8 af[4], bw[2];
            #pragma unroll
            for (int i = 0; i < 4; i++)
                af[i] = *(const bf16x8*)(ta + (wm + i * 16 + l16) * 64 + pu);
            #pragma unroll
            for (int j = 0; j < 2; j++)
                bw[j] = *(const bf16x8*)(tb + (wn + j * 16 + l16) * 64 + pu);
            #pragma unroll
            for (int i = 0; i < 4; i++)
                #pragma unroll
                for (int j = 0; j < 2; j++)
                    acc[i][j] = mfma16(af[i], bw[j], acc[i][j]);
        }
    }

    #pragma unroll
    for (int i = 0; i < 4; i++) {
        #pragma unroll
        for (int j = 0; j < 2; j++) {
            const int row0 = m0 + wm + i * 16 + quad * 4;
            const int col  = n0 + wn + j * 16 + l16;
            if (f32out) {
                float* cp = (float*)C + (size_t)row0 * CDIM + col;
                #pragma unroll
                for (int r = 0; r < 4; r++)
                    cp[(size_t)r * CDIM] = acc[i][j][r];
            } else {
                short* cp = (short*)C + (size_t)row0 * CDIM + col;
                #pragma unroll
                for (int r = 0; r < 4; r++)
                    cp[(size_t)r * CDIM] = f2bf(acc[i][j][r]);
            }
        }
    }
}

// ---------------------------------------------------------------------------
// Flash attention, S^T form, fixed-max softmax, 2-way K-SPLIT.
// v5 (= v4 minus inline-asm cvt_pk; pk2 packing only):
//  - l computed by ones-vector MFMA (l = P . 1) fused into the PV cluster:
//    removes the 64-deep serial scalar add chain per tile AND the final
//    cross-quad shuffles; l sums the same bf16 P used in the numerator.
//  - T5: s_setprio(1) around QK and PV MFMA clusters.
__global__ __launch_bounds__(256, 2) void attn_t(
    const short* __restrict__ Q, const short* __restrict__ K,
    const short* __restrict__ VT,
    short* __restrict__ P0, short* __restrict__ P1, float* __restrict__ L)
{
    const int h = blockIdx.x;
    const int b = blockIdx.y;
    // z -> (qt2, p): snake-balanced quadruples; co-resident items sum ~17
    const int z = blockIdx.z;
    const int g = z >> 3;
    const int item = (g == 1) ? (23 - z) : (g == 3) ? (55 - z) : z;
    const int qt2 = 15 - (item >> 1);
    const int p   = item & 1;
    const int nktall = qt2 + 1;               // total 128-key tiles for supertile

    const int tid  = threadIdx.x;
    const int lane = tid & 63;
    const int wave = tid >> 6;
    const int quad = lane >> 4;
    const int l16  = lane & 15;

    __shared__ __align__(16) short Kt[128][72];       // K tile [key][d]      18432 B
    __shared__ __align__(16) short Vt[64][136];       // V^T tile [d][pkey]   17408 B

    const int rowBase = b * SEQ;
    const int colH    = h * HD;
    const int qgA     = qt2 * 128 + wave * 16 + l16;  // strip A q row
    const int qgB     = qgA + 64;                     // strip B q row

    bf16x8 qa0, qa1, qc0, qc1;
    {
        const short* qp = Q + (size_t)(rowBase + qgA) * CDIM + colH + quad * 8;
        qa0 = *(const bf16x8*)qp;
        qa1 = *(const bf16x8*)(qp + 32);
        const short* qp2 = qp + (size_t)64 * CDIM;
        qc0 = *(const bf16x8*)qp2;
        qc1 = *(const bf16x8*)(qp2 + 32);
    }

    floatx4 oA[4], oB[4];
    #pragma unroll
    for (int nd = 0; nd < 4; nd++) { oA[nd] = 0.0f; oB[nd] = 0.0f; }
    floatx4 lAv = 0.0f, lBv = 0.0f;           // ones-MFMA row-sum accumulators
    const bf16x8 ones = mk8(0x3F803F80u, 0x3F803F80u, 0x3F803F80u, 0x3F803F80u);

    // K staging: thread t -> key = t>>1, d-chunk (t&1)*32 (4 x b128)
    const int kk = tid >> 1;
    const int kd = (tid & 1) * 32;
    const short* kg = K + (size_t)(rowBase + kk) * CDIM + colH + kd;
    // V^T staging: thread t -> d = t>>2, 32-key chunk (t&3)*32 (4 x b128 load,
    // 8 x b64 permuted store)
    const int sd = tid >> 2;
    const int sk = (tid & 3) * 32;
    const short* vg = VT + ((size_t)(b * NH + h) * HD + sd) * SEQ + sk;

    // prefetch first tile of this split into NAMED registers (no arrays: spill)
    const short* kg0 = kg + (size_t)p * 128 * CDIM;
    const short* vg0 = vg + p * 128;
    uint4 ka_0 = *(const uint4*)(kg0);
    uint4 ka_1 = *(const uint4*)(kg0 + 8);
    uint4 ka_2 = *(const uint4*)(kg0 + 16);
    uint4 ka_3 = *(const uint4*)(kg0 + 24);
    uint4 va_0 = *(const uint4*)(vg0);
    uint4 va_1 = *(const uint4*)(vg0 + 8);
    uint4 va_2 = *(const uint4*)(vg0 + 16);
    uint4 va_3 = *(const uint4*)(vg0 + 24);

    const float SCL = 0.18033688011112042f;   // 0.125 * log2(e)

    for (int kt = p; kt < nktall; kt += 2) {
        __syncthreads();                 // prev tile's LDS reads done
        *(uint4*)&Kt[kk][kd]      = ka_0;
        *(uint4*)&Kt[kk][kd + 8]  = ka_1;
        *(uint4*)&Kt[kk][kd + 16] = ka_2;
        *(uint4*)&Kt[kk][kd + 24] = ka_3;
        // permuted V scatter: key offset o=16h+4q+r -> col 8q+4h+r
        {
            short* vrow = &Vt[sd][sk];
            *(uint2*)(vrow + 0)  = make_uint2(va_0.x, va_0.y);   // keys  0-3
            *(uint2*)(vrow + 8)  = make_uint2(va_0.z, va_0.w);   // keys  4-7
            *(uint2*)(vrow + 16) = make_uint2(va_1.x, va_1.y);   // keys  8-11
            *(uint2*)(vrow + 24) = make_uint2(va_1.z, va_1.w);   // keys 12-15
            *(uint2*)(vrow + 4)  = make_uint2(va_2.x, va_2.y);   // keys 16-19
            *(uint2*)(vrow + 12) = make_uint2(va_2.z, va_2.w);   // keys 20-23
            *(uint2*)(vrow + 20) = make_uint2(va_3.x, va_3.y);   // keys 24-27
            *(uint2*)(vrow + 28) = make_uint2(va_3.z, va_3.w);   // keys 28-31
        }
        __syncthreads();                 // tiles ready

        if (kt + 2 < nktall) {           // prefetch next tile of this split
            const short* kn = kg + (size_t)(kt + 2) * 128 * CDIM;
            const short* vn = vg + (kt + 2) * 128;
            ka_0 = *(const uint4*)(kn);
            ka_1 = *(const uint4*)(kn + 8);
            ka_2 = *(const uint4*)(kn + 16);
            ka_3 = *(const uint4*)(kn + 24);
            va_0 = *(const uint4*)(vn);
            va_1 = *(const uint4*)(vn + 8);
            va_2 = *(const uint4*)(vn + 16);
            va_3 = *(const uint4*)(vn + 24);
        }

        const int key0 = kt * 128;
        const bool masked = (kt == nktall - 1);  // diagonal tile (one split only)

        // QK^T + softmax + fused PV. P stays in registers: even ms -> hold
        // packs; odd ms -> complete kc=ms>>1 fragment and issue PV MFMAs.
        unsigned hA0 = 0, hA1 = 0, hB0 = 0, hB1 = 0;
        #pragma unroll
        for (int ms = 0; ms < 8; ms++) {
            const short* kp = &Kt[ms * 16 + l16][quad * 8];
            bf16x8 k0 = *(const bf16x8*)kp;
            bf16x8 k1 = *(const bf16x8*)(kp + 32);
            floatx4 sA = {0.f, 0.f, 0.f, 0.f};
            floatx4 sB = {0.f, 0.f, 0.f, 0.f};
            __builtin_amdgcn_s_setprio(1);
            sA = mfma16(k0, qa0, sA);
            sB = mfma16(k0, qc0, sB);
            sA = mfma16(k1, qa1, sA);
            sB = mfma16(k1, qc1, sB);
            __builtin_amdgcn_s_setprio(0);
            float pA[4], pB[4];
            #pragma unroll
            for (int r = 0; r < 4; r++) {
                const int kgl = key0 + ms * 16 + quad * 4 + r;
                float eA = __builtin_amdgcn_exp2f(sA[r] * SCL);
                float eB = __builtin_amdgcn_exp2f(sB[r] * SCL);
                if (masked) {
                    if (kgl > qgA) eA = 0.0f;
                    if (kgl > qgB) eB = 0.0f;
                }
                pA[r] = eA;
                pB[r] = eB;
            }
            const unsigned cA0 = pk2(pA[0], pA[1]);
            const unsigned cA1 = pk2(pA[2], pA[3]);
            const unsigned cB0 = pk2(pB[0], pB[1]);
            const unsigned cB1 = pk2(pB[2], pB[3]);
            if ((ms & 1) == 0) {
                hA0 = cA0; hA1 = cA1; hB0 = cB0; hB1 = cB1;
            } else {
                const int kc = ms >> 1;
                const bf16x8 pbA = mk8(hA0, hA1, cA0, cA1);
                const bf16x8 pbB = mk8(hB0, hB1, cB0, cB1);
                __builtin_amdgcn_s_setprio(1);
                #pragma unroll
                for (int nd = 0; nd < 4; nd++) {
                    const bf16x8 va = *(const bf16x8*)&Vt[nd * 16 + l16][kc * 32 + quad * 8];
                    oA[nd] = mfma16(va, pbA, oA[nd]);
                    oB[nd] = mfma16(va, pbB, oB[nd]);
                }
                // l = P . ones: row sum lands replicated in every (quad, r)
                lAv = mfma16(ones, pbA, lAv);
                lBv = mfma16(ones, pbB, lBv);
                __builtin_amdgcn_s_setprio(0);
            }
        }
    }

    // every lane already holds the full row sum (replicated); no shuffles
    const float lA = lAv[0];
    const float lB = lBv[0];

    // store UNNORMALIZED partial O (bf16) + l (f32) for this split
    short* Pp = p ? P1 : P0;
    float* Lp = L + p * (NBATCH * NH * SEQ);
    short* opA = Pp + (size_t)(rowBase + qgA) * CDIM + colH;
    short* opB = Pp + (size_t)(rowBase + qgB) * CDIM + colH;
    #pragma unroll
    for (int nd = 0; nd < 4; nd++) {
        *(uint2*)(opA + nd * 16 + quad * 4) =
            make_uint2(pk2(oA[nd][0], oA[nd][1]), pk2(oA[nd][2], oA[nd][3]));
        *(uint2*)(opB + nd * 16 + quad * 4) =
            make_uint2(pk2(oB[nd][0], oB[nd][1]), pk2(oB[nd][2], oB[nd][3]));
    }
    if (quad == 0) {
        Lp[(b * NH + h) * SEQ + qgA] = lA;
        Lp[(b * NH + h) * SEQ + qgB] = lB;
    }
}

// ---------------------------------------------------------------------------
// Combine the two K-split partials: Ob = (P0 + P1) / (l0 + l1), bf16 out.
__global__ void combine(const short* __restrict__ P0, const short* __restrict__ P1,
                        const float* __restrict__ L, short* __restrict__ Ob)
{
    const int i = blockIdx.x * blockDim.x + threadIdx.x;   // 8-short chunk
    const int row = i >> 7;            // 128 chunks per 1024-col row
    const int c8  = i & 127;
    const int h   = c8 >> 3;           // 8 chunks per 64-wide head
    const int b   = row >> 11;
    const int q   = row & 2047;
    const int li  = (b * NH + h) * SEQ + q;
    const float inv = 1.0f / (L[li] + L[NBATCH * NH * SEQ + li]);

    const bf16x8 a0 = ((const bf16x8*)P0)[i];
    const bf16x8 a1 = ((const bf16x8*)P1)[i];
    unsigned d[4];
    #pragma unroll
    for (int e = 0; e < 4; e++) {
        const float lo = (bf2f(a0[2 * e])     + bf2f(a1[2 * e]))     * inv;
        const float hi = (bf2f(a0[2 * e + 1]) + bf2f(a1[2 * e + 1])) * inv;
        d[e] = pk2(lo, hi);
    }
    ((uint4*)Ob)[i] = make_uint4(d[0], d[1], d[2], d[3]);
}

extern "C" void kernel_launch(void* const* d_in, const int* in_sizes, int n_in,
                              void* d_out, int out_size, void* d_ws, size_t ws_size,
                              hipStream_t stream)
{
    const void* x  = d_in[0];
    const void* wq = d_in[1];
    const void* wk = d_in[2];
    const void* wv = d_in[3];
    const void* wo = d_in[4];

    int* flag = (int*)d_ws;
    short* w = (short*)((char*)d_ws + 256);
    const int ME  = 1024 * 1024;
    short* Wqc = w;                            // 4 x 1M elems
    short* Wkc = w + 1 * ME;
    short* Wvc = w + 2 * ME;
    short* Woc = w + 3 * ME;
    short* Xc  = w + 4 * ME;                   // 4M (later: P0 partials -> Ob)
    short* Qb  = w + 8 * ME;
    short* Kb  = w + 12 * ME;
    short* VTb = w + 16 * ME;                  // V^T [b][h][d][key]
    short* P1b = w + 20 * ME;                  // split-1 partial O
    float* Lb  = (float*)(w + 24 * ME);        // 2 x 65536 f32 row sums
    short* P0b = Xc;                           // split-0 partials (Xc dead)
    short* Ob  = Xc;                           // combine writes in place
    // total: 48.5 MB + 256 B

    dim3 blk(256);
    convert_all<<<dim3(512, 5), blk, 0, stream>>>(
        x, wq, wk, wv, wo, Xc, Wqc, Wkc, Wvc, Woc, flag);

    // QKV projection; V written transposed to VTb
    gemm_bt128<<<dim3(MROWS / 128, 24), blk, 0, stream>>>(
        Xc, Wqc, Wkc, Wvc, Qb, Kb, nullptr, VTb, nullptr);
    // causal flash attention, 2-way K-split partials
    attn_t<<<dim3(NH, NBATCH, 32), blk, 0, stream>>>(Qb, Kb, VTb, P0b, P1b, Lb);
    // combine partials -> Ob
    combine<<<dim3(MROWS * CDIM / 8 / 256), blk, 0, stream>>>(P0b, P1b, Lb, Ob);
    // output projection (128x64 tiles -> 512 blocks)
    gemm_n64<<<dim3(MROWS / 128, CDIM / 64), blk, 0, stream>>>(
        Ob, Woc, d_out, flag);
}